// Round 12
// baseline (291.330 us; speedup 1.0000x reference)
//
#include <hip/hip_runtime.h>
#include <hip/hip_bf16.h>

#define NHEAD 4
#define NEG 0.2f

typedef __bf16 bf16x8 __attribute__((ext_vector_type(8)));
typedef __bf16 bf16x4 __attribute__((ext_vector_type(4)));
typedef float f32x4 __attribute__((ext_vector_type(4)));

__device__ __forceinline__ float blo(unsigned u) { return __uint_as_float(u << 16); }
__device__ __forceinline__ float bhi(unsigned u) { return __uint_as_float(u & 0xffff0000u); }
__device__ __forceinline__ unsigned short fbits(float f) {
    __bf16 h = (__bf16)f;
    return *(unsigned short*)&h;
}

// ---------------- CSR build ----------------

__global__ __launch_bounds__(256) void hist_k(const int* __restrict__ dst,
                                              int* __restrict__ deg, int E) {
    int e = blockIdx.x * 256 + threadIdx.x;
    if (e < E) atomicAdd(&deg[dst[e]], 1);
}

__global__ __launch_bounds__(256) void partial_k(const int* __restrict__ deg,
                                                 int* __restrict__ bsum, int n) {
    int t = threadIdx.x;
    int base = blockIdx.x * 2048 + t * 8;
    int s = 0;
#pragma unroll
    for (int i = 0; i < 8; ++i) {
        int idx = base + i;
        if (idx < n) s += deg[idx];
    }
#pragma unroll
    for (int off = 32; off; off >>= 1) s += __shfl_down(s, off, 64);
    __shared__ int ws[4];
    if ((t & 63) == 0) ws[t >> 6] = s;
    __syncthreads();
    if (t == 0) bsum[blockIdx.x] = ws[0] + ws[1] + ws[2] + ws[3];
}

__global__ __launch_bounds__(256) void bscan_k(const int* __restrict__ bsum,
                                               int* __restrict__ boff, int nb) {
    __shared__ int sh[256];
    int t = threadIdx.x;
    int v = (t < nb) ? bsum[t] : 0;
    sh[t] = v;
    __syncthreads();
    for (int off = 1; off < 256; off <<= 1) {
        int u = (t >= off) ? sh[t - off] : 0;
        __syncthreads();
        sh[t] += u;
        __syncthreads();
    }
    if (t < nb) boff[t] = sh[t] - v;  // exclusive
}

__global__ __launch_bounds__(256) void rescan_k(const int* __restrict__ deg,
                                                const int* __restrict__ boff,
                                                int* __restrict__ rowptr,
                                                int* __restrict__ fill,
                                                int n, int total) {
    __shared__ int ts[256];
    int t = threadIdx.x;
    int base = blockIdx.x * 2048 + t * 8;
    int v[8];
    int s = 0;
#pragma unroll
    for (int i = 0; i < 8; ++i) {
        int idx = base + i;
        v[i] = (idx < n) ? deg[idx] : 0;
        s += v[i];
    }
    ts[t] = s;
    __syncthreads();
    for (int off = 1; off < 256; off <<= 1) {
        int u = (t >= off) ? ts[t - off] : 0;
        __syncthreads();
        ts[t] += u;
        __syncthreads();
    }
    int run = boff[blockIdx.x] + ts[t] - s;
#pragma unroll
    for (int i = 0; i < 8; ++i) {
        int idx = base + i;
        if (idx < n) {
            rowptr[idx] = run;
            fill[idx] = run;
            run += v[i];
        }
    }
    if (blockIdx.x == 0 && t == 0) rowptr[n] = total;
}

__global__ __launch_bounds__(256) void scatter_k(const int* __restrict__ src,
                                                 const int* __restrict__ dst,
                                                 const float* __restrict__ ew,
                                                 int* __restrict__ fill,
                                                 int* __restrict__ srcs,
                                                 float* __restrict__ wsrt, int E) {
    int e = blockIdx.x * 256 + threadIdx.x;
    if (e < E) {
        int d = dst[e];
        int p = atomicAdd(&fill[d], 1);
        srcs[p] = src[e];
        wsrt[p] = ew[e];
    }
}

// ---------------- prep: v_h = W_h . att_h, c_h = b_h . att_h (all 3 layers) ----------------

__global__ __launch_bounds__(256) void prep_k(const float* __restrict__ W1, const float* __restrict__ att1, const float* __restrict__ b1,
                                              const float* __restrict__ W2, const float* __restrict__ att2, const float* __restrict__ b2,
                                              const float* __restrict__ W3, const float* __restrict__ att3, const float* __restrict__ b3,
                                              float* __restrict__ v1, float* __restrict__ v2, float* __restrict__ v3,
                                              float* __restrict__ c1, float* __restrict__ c2, float* __restrict__ c3) {
    int tid = blockIdx.x * 256 + threadIdx.x;
    if (tid < 512) {
        int h = tid >> 7, k = tid & 127;
        float p = 0.f;
        for (int d = 0; d < 64; ++d) p += W1[k * 256 + h * 64 + d] * att1[h * 64 + d];
        v1[h * 128 + k] = p;
    } else if (tid < 768) {
        int t = tid - 512, h = t >> 6, k = t & 63;
        float p = 0.f;
        for (int d = 0; d < 64; ++d) p += W2[k * 256 + h * 64 + d] * att2[h * 64 + d];
        v2[h * 64 + k] = p;
    } else if (tid < 1024) {
        int t = tid - 768, h = t >> 6, k = t & 63;
        float p = 0.f;
        for (int d = 0; d < 128; ++d) p += W3[k * 512 + h * 128 + d] * att3[h * 128 + d];
        v3[h * 64 + k] = p;
    } else if (tid < 1028) {
        int h = tid - 1024;
        float p = 0.f;
        for (int d = 0; d < 64; ++d) p += b1[h * 64 + d] * att1[h * 64 + d];
        c1[h] = p;
    } else if (tid < 1032) {
        int h = tid - 1028;
        float p = 0.f;
        for (int d = 0; d < 64; ++d) p += b2[h * 64 + d] * att2[h * 64 + d];
        c2[h] = p;
    } else if (tid < 1036) {
        int h = tid - 1032;
        float p = 0.f;
        for (int d = 0; d < 128; ++d) p += b3[h * 128 + d] * att3[h * 128 + d];
        c3[h] = p;
    }
}

// ---------------- stacked W packs: Ws[d][h*K+k] = W[k][h*D+d], bf16 ----------------

__global__ __launch_bounds__(256) void wpack3_k(const float* __restrict__ W1,
                                                const float* __restrict__ W2,
                                                const float* __restrict__ W3,
                                                unsigned short* __restrict__ Ws1,
                                                unsigned short* __restrict__ Ws2,
                                                unsigned short* __restrict__ Ws3) {
    int tid = blockIdx.x * 256 + threadIdx.x;
    if (tid < 32768) {
        int d = tid >> 9, r = tid & 511, h = r >> 7, k = r & 127;
        Ws1[tid] = fbits(W1[k * 256 + h * 64 + d]);
    } else if (tid < 49152) {
        int t = tid - 32768;
        int d = t >> 8, r = t & 255, h = r >> 6, k = r & 63;
        Ws2[t] = fbits(W2[k * 256 + h * 64 + d]);
    } else if (tid < 81920) {
        int t = tid - 49152;
        int d = t >> 8, r = t & 255, h = r >> 6, k = r & 63;
        Ws3[t] = fbits(W3[k * 512 + h * 128 + d]);
    }
}

// ---------------- x pack to bf16 + layer-1 scores ----------------

__global__ __launch_bounds__(256) void xpack_score_k(const float* __restrict__ x,
                                                     const float* __restrict__ v1,
                                                     const float* __restrict__ c1,
                                                     unsigned* __restrict__ xb,
                                                     float* __restrict__ s, int n) {
    int gt = blockIdx.x * 256 + threadIdx.x;
    int node = gt >> 6, lane = gt & 63;
    if (node >= n) return;
    float2 xv = ((const float2*)(x + (size_t)node * 128))[lane];
    xb[(size_t)node * 64 + lane] = (unsigned)fbits(xv.x) | ((unsigned)fbits(xv.y) << 16);
    int d0 = 2 * lane;
    float p0 = xv.x * v1[0 * 128 + d0] + xv.y * v1[0 * 128 + d0 + 1];
    float p1 = xv.x * v1[1 * 128 + d0] + xv.y * v1[1 * 128 + d0 + 1];
    float p2 = xv.x * v1[2 * 128 + d0] + xv.y * v1[2 * 128 + d0 + 1];
    float p3 = xv.x * v1[3 * 128 + d0] + xv.y * v1[3 * 128 + d0 + 1];
#pragma unroll
    for (int off = 32; off; off >>= 1) {
        p0 += __shfl_xor(p0, off, 64);
        p1 += __shfl_xor(p1, off, 64);
        p2 += __shfl_xor(p2, off, 64);
        p3 += __shfl_xor(p3, off, 64);
    }
    if (lane == 0)
        *(float4*)&s[(size_t)node * 4] = make_float4(p0 + c1[0], p1 + c1[1], p2 + c1[2], p3 + c1[3]);
}

// ---------------- per-edge alpha (once per edge) ----------------

__global__ __launch_bounds__(256) void alpha_k(const int* __restrict__ srcs,
                                               const float* __restrict__ wsrt,
                                               const float* __restrict__ s,
                                               float* __restrict__ alpha, int E) {
    int e = blockIdx.x * 256 + threadIdx.x;
    if (e >= E) return;
    int sn = srcs[e];
    float w = wsrt[e];
    float4 sv = *(const float4*)&s[(size_t)sn * NHEAD];
    float a0 = (sv.x > 0.f ? sv.x : NEG * sv.x) * w;
    float a1 = (sv.y > 0.f ? sv.y : NEG * sv.y) * w;
    float a2 = (sv.z > 0.f ? sv.z : NEG * sv.z) * w;
    float a3 = (sv.w > 0.f ? sv.w : NEG * sv.w) * w;
    float m = fmaxf(fmaxf(a0, a1), fmaxf(a2, a3));
    float e0 = __expf(a0 - m), e1 = __expf(a1 - m);
    float e2 = __expf(a2 - m), e3 = __expf(a3 - m);
    float inv = 0.25f / (e0 + e1 + e2 + e3);
    *(float4*)&alpha[(size_t)e * 4] = make_float4(e0 * inv, e1 * inv, e2 * inv, e3 * inv);
}

// ---------------- fused layer: gather -> single LDS buffer, TWO MFMA passes (hi, lo)
//                  -> epilogue. Halved LDS doubles occupancy; numerics identical to
//                  the simultaneous hi/lo version. ----------------

template <int K, int D, bool LAST>
__global__ __launch_bounds__(256, 4) void fused_k(const int* __restrict__ rowptr,
                                                  const int* __restrict__ srcs,
                                                  const float* __restrict__ alpha,
                                                  const unsigned* __restrict__ xb,
                                                  const unsigned short* __restrict__ Ws,
                                                  const float* __restrict__ bias,
                                                  const float* __restrict__ vnext,
                                                  const float* __restrict__ cnext,
                                                  unsigned short* __restrict__ aout,
                                                  float* __restrict__ fout,
                                                  float* __restrict__ snext,
                                                  int n) {
    constexpr int HK = 4 * K;
    constexpr int KS = HK / 32;
    constexpr int NC = D / 16;
    constexpr int CW = NC / 4;
    constexpr int DW = K / 32;

    __shared__ __bf16 g[16 * HK];          // single staging buffer (hi pass, then lo pass)
    __shared__ float4 A_lds[16];
    __shared__ float4 sc_lds[4][16];

    int t = threadIdx.x;
    int r0 = blockIdx.x * 16;
    int n4 = t >> 4, sl = t & 15;
    int node = r0 + n4;

    // ---- gather phase (simple 4-edge unroll — R8 form) ----
    float acc[4][2 * DW];
#pragma unroll
    for (int h = 0; h < 4; ++h)
#pragma unroll
        for (int j = 0; j < 2 * DW; ++j) acc[h][j] = 0.f;
    float4 aA = make_float4(0.f, 0.f, 0.f, 0.f);

    auto load_u = [&](int sn, unsigned* u) {
        if constexpr (DW == 4) {
            uint4 ta = ((const uint4*)xb)[(size_t)sn * 16 + sl];
            u[0] = ta.x; u[1] = ta.y; u[2] = ta.z; u[3] = ta.w;
        } else {
            uint2 ta = ((const uint2*)xb)[(size_t)sn * 16 + sl];
            u[0] = ta.x; u[1] = ta.y;
        }
    };
    auto accum = [&](float4 al, const unsigned* u) {
#pragma unroll
        for (int j = 0; j < DW; ++j) {
            float x0 = blo(u[j]), x1 = bhi(u[j]);
            acc[0][2 * j] += al.x * x0; acc[0][2 * j + 1] += al.x * x1;
            acc[1][2 * j] += al.y * x0; acc[1][2 * j + 1] += al.y * x1;
            acc[2][2 * j] += al.z * x0; acc[2][2 * j + 1] += al.z * x1;
            acc[3][2 * j] += al.w * x0; acc[3][2 * j + 1] += al.w * x1;
        }
        aA.x += al.x; aA.y += al.y; aA.z += al.z; aA.w += al.w;
    };

    if (node < n) {
        int beg = rowptr[node], end = rowptr[node + 1];
        int e = beg;
        for (; e + 3 < end; e += 4) {
            int sn0 = srcs[e], sn1 = srcs[e + 1], sn2 = srcs[e + 2], sn3 = srcs[e + 3];
            unsigned u0[DW], u1[DW], u2[DW], u3[DW];
            load_u(sn0, u0); load_u(sn1, u1); load_u(sn2, u2); load_u(sn3, u3);
            float4 al0 = *(const float4*)&alpha[(size_t)e * 4];
            float4 al1 = *(const float4*)&alpha[(size_t)(e + 1) * 4];
            float4 al2 = *(const float4*)&alpha[(size_t)(e + 2) * 4];
            float4 al3 = *(const float4*)&alpha[(size_t)(e + 3) * 4];
            accum(al0, u0); accum(al1, u1); accum(al2, u2); accum(al3, u3);
        }
        for (; e < end; ++e) {
            int sn = srcs[e];
            unsigned u[DW];
            load_u(sn, u);
            float4 al = *(const float4*)&alpha[(size_t)e * 4];
            accum(al, u);
        }
    }

    // ---- helpers: LDS write (swizzled) and one MFMA pass ----
    int wid = t >> 6, lane = t & 63;
    int lrow = lane & 15, gq = lane >> 4;

    auto write_part = [&](bool lo) {
        char* gb = (char*)g + (size_t)n4 * (HK * 2);
        int sw = (n4 & 7) << 4;
#pragma unroll
        for (int h = 0; h < 4; ++h) {
            if constexpr (DW == 4) {
                bf16x8 v;
#pragma unroll
                for (int j = 0; j < 8; ++j) {
                    float a = acc[h][j];
                    __bf16 hi = (__bf16)a;
                    v[j] = lo ? (__bf16)(a - (float)hi) : hi;
                }
                int bo = (h * K + sl * 8) * 2;
                *(bf16x8*)(gb + (bo ^ sw)) = v;
            } else {
                bf16x4 v;
#pragma unroll
                for (int j = 0; j < 4; ++j) {
                    float a = acc[h][j];
                    __bf16 hi = (__bf16)a;
                    v[j] = lo ? (__bf16)(a - (float)hi) : hi;
                }
                int bo = (h * K + sl * 4) * 2;
                *(bf16x4*)(gb + (bo ^ sw)) = v;
            }
        }
    };

    f32x4 acc2[CW];
#pragma unroll
    for (int cw = 0; cw < CW; ++cw)
#pragma unroll
        for (int r = 0; r < 4; ++r) acc2[cw][r] = 0.f;

    const __bf16* wsp = (const __bf16*)Ws;
    const char* gr = (const char*)g + (size_t)lrow * (HK * 2);
    int swr = (lrow & 7) << 4;

    auto mfma_pass = [&]() {
#pragma unroll
        for (int ks = 0; ks < KS; ++ks) {
            int bo = ks * 64 + gq * 16;
            bf16x8 fr = *(const bf16x8*)(gr + (bo ^ swr));
#pragma unroll
            for (int cw = 0; cw < CW; ++cw) {
                int c = wid * CW + cw;
                bf16x8 bfr = *(const bf16x8*)(wsp + (size_t)(c * 16 + lrow) * HK + ks * 32 + gq * 8);
                acc2[cw] = __builtin_amdgcn_mfma_f32_16x16x32_bf16(fr, bfr, acc2[cw], 0, 0, 0);
            }
        }
    };

    // ---- pass 1: hi ----
    write_part(false);
    if (sl == 0) A_lds[n4] = aA;
    __syncthreads();
    mfma_pass();
    __syncthreads();
    // ---- pass 2: lo ----
    write_part(true);
    __syncthreads();
    mfma_pass();

    // ---- epilogue ----
    float4 Ar[4];
#pragma unroll
    for (int r = 0; r < 4; ++r) Ar[r] = A_lds[gq * 4 + r];

    float sc[4][4];
#pragma unroll
    for (int h = 0; h < 4; ++h)
#pragma unroll
        for (int r = 0; r < 4; ++r) sc[h][r] = 0.f;

#pragma unroll
    for (int cw = 0; cw < CW; ++cw) {
        int col = (wid * CW + cw) * 16 + lrow;
        float bb0 = bias[0 * D + col], bb1 = bias[1 * D + col];
        float bb2 = bias[2 * D + col], bb3 = bias[3 * D + col];
        float vv0 = 0.f, vv1 = 0.f, vv2 = 0.f, vv3 = 0.f;
        if constexpr (!LAST) {
            vv0 = vnext[0 * D + col]; vv1 = vnext[1 * D + col];
            vv2 = vnext[2 * D + col]; vv3 = vnext[3 * D + col];
        }
#pragma unroll
        for (int r = 0; r < 4; ++r) {
            float val = acc2[cw][r] + Ar[r].x * bb0 + Ar[r].y * bb1 + Ar[r].z * bb2 + Ar[r].w * bb3;
            int row = r0 + gq * 4 + r;
            if constexpr (LAST) {
                if (row < n) fout[(size_t)row * D + col] = val;
            } else {
                val = fmaxf(val, 0.f);
                if (row < n) aout[(size_t)row * D + col] = fbits(val);
                sc[0][r] += val * vv0;
                sc[1][r] += val * vv1;
                sc[2][r] += val * vv2;
                sc[3][r] += val * vv3;
            }
        }
    }

    if constexpr (!LAST) {
#pragma unroll
        for (int m = 1; m < 16; m <<= 1) {
#pragma unroll
            for (int h = 0; h < 4; ++h)
#pragma unroll
                for (int r = 0; r < 4; ++r) sc[h][r] += __shfl_xor(sc[h][r], m, 64);
        }
        if (lrow < 4) {
            int r = lrow;
            sc_lds[wid][gq * 4 + r] = make_float4(sc[0][r], sc[1][r], sc[2][r], sc[3][r]);
        }
        __syncthreads();
        if (t < 16) {
            int row = r0 + t;
            if (row < n) {
                float4 s0 = sc_lds[0][t], s1 = sc_lds[1][t];
                float4 s2 = sc_lds[2][t], s3 = sc_lds[3][t];
                *(float4*)&snext[(size_t)row * 4] =
                    make_float4(s0.x + s1.x + s2.x + s3.x + cnext[0],
                                s0.y + s1.y + s2.y + s3.y + cnext[1],
                                s0.z + s1.z + s2.z + s3.z + cnext[2],
                                s0.w + s1.w + s2.w + s3.w + cnext[3]);
            }
        }
    }
}

// ---------------- launch ----------------

extern "C" void kernel_launch(void* const* d_in, const int* in_sizes, int n_in,
                              void* d_out, int out_size, void* d_ws, size_t ws_size,
                              hipStream_t stream) {
    const float* x    = (const float*)d_in[0];
    const int*   ei   = (const int*)d_in[1];
    const float* ew   = (const float*)d_in[2];
    const float* W1   = (const float*)d_in[3];
    const float* b1   = (const float*)d_in[4];
    const float* att1 = (const float*)d_in[5];
    const float* W2   = (const float*)d_in[6];
    const float* b2   = (const float*)d_in[7];
    const float* att2 = (const float*)d_in[8];
    const float* W3   = (const float*)d_in[9];
    const float* b3   = (const float*)d_in[10];
    const float* att3 = (const float*)d_in[11];

    const int N = in_sizes[0] / 128;
    const int E = in_sizes[2];
    const int* src = ei;
    const int* dst = ei + E;

    char* wp = (char*)d_ws;
    auto alloc = [&](size_t bytes) -> void* {
        void* p = (void*)wp;
        wp += (bytes + 511) & ~(size_t)511;
        return p;
    };
    int*   deg    = (int*)alloc((size_t)N * 4);
    int*   rowptr = (int*)alloc((size_t)(N + 1) * 4);
    int*   fill   = (int*)alloc((size_t)N * 4);
    int*   bsum   = (int*)alloc(256 * 4);
    int*   boff   = (int*)alloc(256 * 4);
    int*   srcs   = (int*)alloc((size_t)E * 4);
    float* wsrt   = (float*)alloc((size_t)E * 4);
    unsigned* xb  = (unsigned*)alloc((size_t)N * 64 * 4);
    float* s      = (float*)alloc((size_t)N * 4 * 4);
    float* s2     = (float*)alloc((size_t)N * 4 * 4);
    float* alpha  = (float*)alloc((size_t)E * 4 * 4);
    unsigned short* a1 = (unsigned short*)alloc((size_t)N * 64 * 2);
    unsigned short* a2 = (unsigned short*)alloc((size_t)N * 64 * 2);
    float* v1 = (float*)alloc(512 * 4);
    float* v2 = (float*)alloc(256 * 4);
    float* v3 = (float*)alloc(256 * 4);
    float* c1 = (float*)alloc(16);
    float* c2 = (float*)alloc(16);
    float* c3 = (float*)alloc(16);
    unsigned short* Ws1 = (unsigned short*)alloc(32768 * 2);
    unsigned short* Ws2 = (unsigned short*)alloc(16384 * 2);
    unsigned short* Ws3 = (unsigned short*)alloc(32768 * 2);

    // --- prep (independent of CSR) ---
    wpack3_k<<<320, 256, 0, stream>>>(W1, W2, W3, Ws1, Ws2, Ws3);
    prep_k<<<5, 256, 0, stream>>>(W1, att1, b1, W2, att2, b2, W3, att3, b3,
                                  v1, v2, v3, c1, c2, c3);
    int gx = (N * 64 + 255) / 256;
    xpack_score_k<<<gx, 256, 0, stream>>>(x, v1, c1, xb, s, N);

    // --- CSR build (shared by all 3 layers) ---
    hipMemsetAsync(deg, 0, (size_t)N * 4, stream);
    int ge = (E + 255) / 256;
    int nb = (N + 2047) / 2048;
    hist_k<<<ge, 256, 0, stream>>>(dst, deg, E);
    partial_k<<<nb, 256, 0, stream>>>(deg, bsum, N);
    bscan_k<<<1, 256, 0, stream>>>(bsum, boff, nb);
    rescan_k<<<nb, 256, 0, stream>>>(deg, boff, rowptr, fill, N, E);
    scatter_k<<<ge, 256, 0, stream>>>(src, dst, ew, fill, srcs, wsrt, E);

    int gf = (N + 15) / 16;

    // --- layer 1 ---
    alpha_k<<<ge, 256, 0, stream>>>(srcs, wsrt, s, alpha, E);
    fused_k<128, 64, false><<<gf, 256, 0, stream>>>(rowptr, srcs, alpha, xb, Ws1, b1,
                                                    v2, c2, a1, nullptr, s2, N);

    // --- layer 2 ---
    alpha_k<<<ge, 256, 0, stream>>>(srcs, wsrt, s2, alpha, E);
    fused_k<64, 64, false><<<gf, 256, 0, stream>>>(rowptr, srcs, alpha, (const unsigned*)a1,
                                                   Ws2, b2, v3, c3, a2, nullptr, s, N);

    // --- layer 3 ---
    alpha_k<<<ge, 256, 0, stream>>>(srcs, wsrt, s, alpha, E);
    fused_k<64, 128, true><<<gf, 256, 0, stream>>>(rowptr, srcs, alpha, (const unsigned*)a2,
                                                   Ws3, b3, nullptr, nullptr, nullptr,
                                                   (float*)d_out, nullptr, N);
}

// Round 13
// 262.419 us; speedup vs baseline: 1.1102x; 1.1102x over previous
//
#include <hip/hip_runtime.h>
#include <hip/hip_bf16.h>

#define NHEAD 4
#define NEG 0.2f

typedef __bf16 bf16x8 __attribute__((ext_vector_type(8)));
typedef __bf16 bf16x4 __attribute__((ext_vector_type(4)));
typedef float f32x4 __attribute__((ext_vector_type(4)));

__device__ __forceinline__ float blo(unsigned u) { return __uint_as_float(u << 16); }
__device__ __forceinline__ float bhi(unsigned u) { return __uint_as_float(u & 0xffff0000u); }
__device__ __forceinline__ unsigned short fbits(float f) {
    __bf16 h = (__bf16)f;
    return *(unsigned short*)&h;
}

// ---------------- CSR build ----------------

__global__ __launch_bounds__(256) void hist_k(const int* __restrict__ dst,
                                              int* __restrict__ deg, int E) {
    int e = blockIdx.x * 256 + threadIdx.x;
    if (e < E) atomicAdd(&deg[dst[e]], 1);
}

__global__ __launch_bounds__(256) void partial_k(const int* __restrict__ deg,
                                                 int* __restrict__ bsum, int n) {
    int t = threadIdx.x;
    int base = blockIdx.x * 2048 + t * 8;
    int s = 0;
#pragma unroll
    for (int i = 0; i < 8; ++i) {
        int idx = base + i;
        if (idx < n) s += deg[idx];
    }
#pragma unroll
    for (int off = 32; off; off >>= 1) s += __shfl_down(s, off, 64);
    __shared__ int ws[4];
    if ((t & 63) == 0) ws[t >> 6] = s;
    __syncthreads();
    if (t == 0) bsum[blockIdx.x] = ws[0] + ws[1] + ws[2] + ws[3];
}

__global__ __launch_bounds__(256) void bscan_k(const int* __restrict__ bsum,
                                               int* __restrict__ boff, int nb) {
    __shared__ int sh[256];
    int t = threadIdx.x;
    int v = (t < nb) ? bsum[t] : 0;
    sh[t] = v;
    __syncthreads();
    for (int off = 1; off < 256; off <<= 1) {
        int u = (t >= off) ? sh[t - off] : 0;
        __syncthreads();
        sh[t] += u;
        __syncthreads();
    }
    if (t < nb) boff[t] = sh[t] - v;  // exclusive
}

__global__ __launch_bounds__(256) void rescan_k(const int* __restrict__ deg,
                                                const int* __restrict__ boff,
                                                int* __restrict__ rowptr,
                                                int* __restrict__ fill,
                                                int n, int total) {
    __shared__ int ts[256];
    int t = threadIdx.x;
    int base = blockIdx.x * 2048 + t * 8;
    int v[8];
    int s = 0;
#pragma unroll
    for (int i = 0; i < 8; ++i) {
        int idx = base + i;
        v[i] = (idx < n) ? deg[idx] : 0;
        s += v[i];
    }
    ts[t] = s;
    __syncthreads();
    for (int off = 1; off < 256; off <<= 1) {
        int u = (t >= off) ? ts[t - off] : 0;
        __syncthreads();
        ts[t] += u;
        __syncthreads();
    }
    int run = boff[blockIdx.x] + ts[t] - s;
#pragma unroll
    for (int i = 0; i < 8; ++i) {
        int idx = base + i;
        if (idx < n) {
            rowptr[idx] = run;
            fill[idx] = run;
            run += v[i];
        }
    }
    if (blockIdx.x == 0 && t == 0) rowptr[n] = total;
}

__global__ __launch_bounds__(256) void scatter_k(const int* __restrict__ src,
                                                 const int* __restrict__ dst,
                                                 const float* __restrict__ ew,
                                                 int* __restrict__ fill,
                                                 int* __restrict__ srcs,
                                                 float* __restrict__ wsrt, int E) {
    int e = blockIdx.x * 256 + threadIdx.x;
    if (e < E) {
        int d = dst[e];
        int p = atomicAdd(&fill[d], 1);
        srcs[p] = src[e];
        wsrt[p] = ew[e];
    }
}

// ---------------- prep: v_h = W_h . att_h, c_h = b_h . att_h (all 3 layers) ----------------

__global__ __launch_bounds__(256) void prep_k(const float* __restrict__ W1, const float* __restrict__ att1, const float* __restrict__ b1,
                                              const float* __restrict__ W2, const float* __restrict__ att2, const float* __restrict__ b2,
                                              const float* __restrict__ W3, const float* __restrict__ att3, const float* __restrict__ b3,
                                              float* __restrict__ v1, float* __restrict__ v2, float* __restrict__ v3,
                                              float* __restrict__ c1, float* __restrict__ c2, float* __restrict__ c3) {
    int tid = blockIdx.x * 256 + threadIdx.x;
    if (tid < 512) {
        int h = tid >> 7, k = tid & 127;
        float p = 0.f;
        for (int d = 0; d < 64; ++d) p += W1[k * 256 + h * 64 + d] * att1[h * 64 + d];
        v1[h * 128 + k] = p;
    } else if (tid < 768) {
        int t = tid - 512, h = t >> 6, k = t & 63;
        float p = 0.f;
        for (int d = 0; d < 64; ++d) p += W2[k * 256 + h * 64 + d] * att2[h * 64 + d];
        v2[h * 64 + k] = p;
    } else if (tid < 1024) {
        int t = tid - 768, h = t >> 6, k = t & 63;
        float p = 0.f;
        for (int d = 0; d < 128; ++d) p += W3[k * 512 + h * 128 + d] * att3[h * 128 + d];
        v3[h * 64 + k] = p;
    } else if (tid < 1028) {
        int h = tid - 1024;
        float p = 0.f;
        for (int d = 0; d < 64; ++d) p += b1[h * 64 + d] * att1[h * 64 + d];
        c1[h] = p;
    } else if (tid < 1032) {
        int h = tid - 1028;
        float p = 0.f;
        for (int d = 0; d < 64; ++d) p += b2[h * 64 + d] * att2[h * 64 + d];
        c2[h] = p;
    } else if (tid < 1036) {
        int h = tid - 1032;
        float p = 0.f;
        for (int d = 0; d < 128; ++d) p += b3[h * 128 + d] * att3[h * 128 + d];
        c3[h] = p;
    }
}

// ---------------- stacked W packs: Ws[d][h*K+k] = W[k][h*D+d], bf16 ----------------

__global__ __launch_bounds__(256) void wpack3_k(const float* __restrict__ W1,
                                                const float* __restrict__ W2,
                                                const float* __restrict__ W3,
                                                unsigned short* __restrict__ Ws1,
                                                unsigned short* __restrict__ Ws2,
                                                unsigned short* __restrict__ Ws3) {
    int tid = blockIdx.x * 256 + threadIdx.x;
    if (tid < 32768) {
        int d = tid >> 9, r = tid & 511, h = r >> 7, k = r & 127;
        Ws1[tid] = fbits(W1[k * 256 + h * 64 + d]);
    } else if (tid < 49152) {
        int t = tid - 32768;
        int d = t >> 8, r = t & 255, h = r >> 6, k = r & 63;
        Ws2[t] = fbits(W2[k * 256 + h * 64 + d]);
    } else if (tid < 81920) {
        int t = tid - 49152;
        int d = t >> 8, r = t & 255, h = r >> 6, k = r & 63;
        Ws3[t] = fbits(W3[k * 512 + h * 128 + d]);
    }
}

// ---------------- x pack to bf16 + layer-1 scores ----------------

__global__ __launch_bounds__(256) void xpack_score_k(const float* __restrict__ x,
                                                     const float* __restrict__ v1,
                                                     const float* __restrict__ c1,
                                                     unsigned* __restrict__ xb,
                                                     float* __restrict__ s, int n) {
    int gt = blockIdx.x * 256 + threadIdx.x;
    int node = gt >> 6, lane = gt & 63;
    if (node >= n) return;
    float2 xv = ((const float2*)(x + (size_t)node * 128))[lane];
    xb[(size_t)node * 64 + lane] = (unsigned)fbits(xv.x) | ((unsigned)fbits(xv.y) << 16);
    int d0 = 2 * lane;
    float p0 = xv.x * v1[0 * 128 + d0] + xv.y * v1[0 * 128 + d0 + 1];
    float p1 = xv.x * v1[1 * 128 + d0] + xv.y * v1[1 * 128 + d0 + 1];
    float p2 = xv.x * v1[2 * 128 + d0] + xv.y * v1[2 * 128 + d0 + 1];
    float p3 = xv.x * v1[3 * 128 + d0] + xv.y * v1[3 * 128 + d0 + 1];
#pragma unroll
    for (int off = 32; off; off >>= 1) {
        p0 += __shfl_xor(p0, off, 64);
        p1 += __shfl_xor(p1, off, 64);
        p2 += __shfl_xor(p2, off, 64);
        p3 += __shfl_xor(p3, off, 64);
    }
    if (lane == 0)
        *(float4*)&s[(size_t)node * 4] = make_float4(p0 + c1[0], p1 + c1[1], p2 + c1[2], p3 + c1[3]);
}

// ---------------- per-edge alpha (once per edge) ----------------

__global__ __launch_bounds__(256) void alpha_k(const int* __restrict__ srcs,
                                               const float* __restrict__ wsrt,
                                               const float* __restrict__ s,
                                               float* __restrict__ alpha, int E) {
    int e = blockIdx.x * 256 + threadIdx.x;
    if (e >= E) return;
    int sn = srcs[e];
    float w = wsrt[e];
    float4 sv = *(const float4*)&s[(size_t)sn * NHEAD];
    float a0 = (sv.x > 0.f ? sv.x : NEG * sv.x) * w;
    float a1 = (sv.y > 0.f ? sv.y : NEG * sv.y) * w;
    float a2 = (sv.z > 0.f ? sv.z : NEG * sv.z) * w;
    float a3 = (sv.w > 0.f ? sv.w : NEG * sv.w) * w;
    float m = fmaxf(fmaxf(a0, a1), fmaxf(a2, a3));
    float e0 = __expf(a0 - m), e1 = __expf(a1 - m);
    float e2 = __expf(a2 - m), e3 = __expf(a3 - m);
    float inv = 0.25f / (e0 + e1 + e2 + e3);
    *(float4*)&alpha[(size_t)e * 4] = make_float4(e0 * inv, e1 * inv, e2 * inv, e3 * inv);
}

// ---------------- fused layer: K-half passes {gather(64 dims) -> stage hi+lo -> MFMA}
//                  -> epilogue. Small per-pass state (acc[4][4]) never lives across a
//                  barrier; LDS 17.9KB. ----------------

template <int K, int D, bool LAST>
__global__ __launch_bounds__(256, 6) void fused_k(const int* __restrict__ rowptr,
                                                  const int* __restrict__ srcs,
                                                  const float* __restrict__ alpha,
                                                  const unsigned* __restrict__ xb,
                                                  const unsigned short* __restrict__ Ws,
                                                  const float* __restrict__ bias,
                                                  const float* __restrict__ vnext,
                                                  const float* __restrict__ cnext,
                                                  unsigned short* __restrict__ aout,
                                                  float* __restrict__ fout,
                                                  float* __restrict__ snext,
                                                  int n) {
    constexpr int HK = 4 * K;
    constexpr int KH = K / 64;        // K-half passes (1 or 2)
    constexpr int NC = D / 16;
    constexpr int CW = NC / 4;
    constexpr int RU2 = K / 4;        // uint2 per xb row

    __shared__ __bf16 gsth[16 * 256];  // per pass: 16 nodes x (4 heads x 64 dims) hi
    __shared__ __bf16 gstl[16 * 256];  // lo
    __shared__ float4 A_lds[16];
    __shared__ float4 sc_lds[4][16];

    int t = threadIdx.x;
    int r0 = blockIdx.x * 16;
    int n4 = t >> 4, sl = t & 15;
    int node = r0 + n4;
    int wid = t >> 6, lane = t & 63;
    int lrow = lane & 15, gq = lane >> 4;

    int beg = 0, end = 0;
    if (node < n) { beg = rowptr[node]; end = rowptr[node + 1]; }

    f32x4 acc2[CW];
#pragma unroll
    for (int cw = 0; cw < CW; ++cw)
#pragma unroll
        for (int r = 0; r < 4; ++r) acc2[cw][r] = 0.f;

    const uint2* xr = (const uint2*)xb;
    const __bf16* wsp = (const __bf16*)Ws;
    const char* ghr = (const char*)gsth + (size_t)lrow * 512;
    const char* glr = (const char*)gstl + (size_t)lrow * 512;
    int swr = (lrow & 7) << 4;

    for (int kh = 0; kh < KH; ++kh) {
        // ---- gather pass kh: dims [kh*64, kh*64+64); lane sl covers 4 dims ----
        float acc[4][4];
#pragma unroll
        for (int h = 0; h < 4; ++h)
#pragma unroll
            for (int j = 0; j < 4; ++j) acc[h][j] = 0.f;
        float4 aA = make_float4(0.f, 0.f, 0.f, 0.f);

        auto accum1 = [&](float4 al, uint2 u) {
            float x0 = blo(u.x), x1 = bhi(u.x), x2 = blo(u.y), x3 = bhi(u.y);
            acc[0][0] += al.x * x0; acc[0][1] += al.x * x1; acc[0][2] += al.x * x2; acc[0][3] += al.x * x3;
            acc[1][0] += al.y * x0; acc[1][1] += al.y * x1; acc[1][2] += al.y * x2; acc[1][3] += al.y * x3;
            acc[2][0] += al.z * x0; acc[2][1] += al.z * x1; acc[2][2] += al.z * x2; acc[2][3] += al.z * x3;
            acc[3][0] += al.w * x0; acc[3][1] += al.w * x1; acc[3][2] += al.w * x2; acc[3][3] += al.w * x3;
            aA.x += al.x; aA.y += al.y; aA.z += al.z; aA.w += al.w;
        };

        int e = beg;
        for (; e + 3 < end; e += 4) {
            int sn0 = srcs[e], sn1 = srcs[e + 1], sn2 = srcs[e + 2], sn3 = srcs[e + 3];
            uint2 u0 = xr[(size_t)sn0 * RU2 + kh * 16 + sl];
            uint2 u1 = xr[(size_t)sn1 * RU2 + kh * 16 + sl];
            uint2 u2 = xr[(size_t)sn2 * RU2 + kh * 16 + sl];
            uint2 u3 = xr[(size_t)sn3 * RU2 + kh * 16 + sl];
            float4 al0 = *(const float4*)&alpha[(size_t)e * 4];
            float4 al1 = *(const float4*)&alpha[(size_t)(e + 1) * 4];
            float4 al2 = *(const float4*)&alpha[(size_t)(e + 2) * 4];
            float4 al3 = *(const float4*)&alpha[(size_t)(e + 3) * 4];
            accum1(al0, u0); accum1(al1, u1); accum1(al2, u2); accum1(al3, u3);
        }
        for (; e < end; ++e) {
            uint2 u = xr[(size_t)srcs[e] * RU2 + kh * 16 + sl];
            float4 al = *(const float4*)&alpha[(size_t)e * 4];
            accum1(al, u);
        }

        if (kh) __syncthreads();  // prev MFMA done reading gst before overwrite

        // ---- stage hi+lo (XOR-swizzled: byte ^= (row&7)<<4) ----
        {
            char* ghb = (char*)gsth + (size_t)n4 * 512;
            char* glb = (char*)gstl + (size_t)n4 * 512;
            int sw = (n4 & 7) << 4;
#pragma unroll
            for (int h = 0; h < 4; ++h) {
                bf16x4 vh, vl;
#pragma unroll
                for (int j = 0; j < 4; ++j) {
                    float a = acc[h][j];
                    __bf16 hi = (__bf16)a;
                    vh[j] = hi;
                    vl[j] = (__bf16)(a - (float)hi);
                }
                int bo = h * 128 + sl * 8;
                *(bf16x4*)(ghb + (bo ^ sw)) = vh;
                *(bf16x4*)(glb + (bo ^ sw)) = vl;
            }
            if (kh == 0 && sl == 0) A_lds[n4] = aA;
        }
        __syncthreads();

        // ---- MFMA pass over this K-half (8 local ks) ----
#pragma unroll
        for (int ksl = 0; ksl < 8; ++ksl) {
            int h = ksl >> 1, kk = ksl & 1;
            int bo = h * 128 + kk * 64 + gq * 16;
            bf16x8 fh = *(const bf16x8*)(ghr + (bo ^ swr));
            bf16x8 fl = *(const bf16x8*)(glr + (bo ^ swr));
#pragma unroll
            for (int cw = 0; cw < CW; ++cw) {
                int c = wid * CW + cw;
                const __bf16* bp = wsp + (size_t)(c * 16 + lrow) * HK + h * K + kh * 64 + kk * 32 + gq * 8;
                bf16x8 bfr = *(const bf16x8*)bp;
                acc2[cw] = __builtin_amdgcn_mfma_f32_16x16x32_bf16(fh, bfr, acc2[cw], 0, 0, 0);
                acc2[cw] = __builtin_amdgcn_mfma_f32_16x16x32_bf16(fl, bfr, acc2[cw], 0, 0, 0);
            }
        }
    }

    // ---- epilogue ----
    float4 Ar[4];
#pragma unroll
    for (int r = 0; r < 4; ++r) Ar[r] = A_lds[gq * 4 + r];

    float sc[4][4];
#pragma unroll
    for (int h = 0; h < 4; ++h)
#pragma unroll
        for (int r = 0; r < 4; ++r) sc[h][r] = 0.f;

#pragma unroll
    for (int cw = 0; cw < CW; ++cw) {
        int col = (wid * CW + cw) * 16 + lrow;
        float bb0 = bias[0 * D + col], bb1 = bias[1 * D + col];
        float bb2 = bias[2 * D + col], bb3 = bias[3 * D + col];
        float vv0 = 0.f, vv1 = 0.f, vv2 = 0.f, vv3 = 0.f;
        if constexpr (!LAST) {
            vv0 = vnext[0 * D + col]; vv1 = vnext[1 * D + col];
            vv2 = vnext[2 * D + col]; vv3 = vnext[3 * D + col];
        }
#pragma unroll
        for (int r = 0; r < 4; ++r) {
            float val = acc2[cw][r] + Ar[r].x * bb0 + Ar[r].y * bb1 + Ar[r].z * bb2 + Ar[r].w * bb3;
            int row = r0 + gq * 4 + r;
            if constexpr (LAST) {
                if (row < n) fout[(size_t)row * D + col] = val;
            } else {
                val = fmaxf(val, 0.f);
                if (row < n) aout[(size_t)row * D + col] = fbits(val);
                sc[0][r] += val * vv0;
                sc[1][r] += val * vv1;
                sc[2][r] += val * vv2;
                sc[3][r] += val * vv3;
            }
        }
    }

    if constexpr (!LAST) {
#pragma unroll
        for (int m = 1; m < 16; m <<= 1) {
#pragma unroll
            for (int h = 0; h < 4; ++h)
#pragma unroll
                for (int r = 0; r < 4; ++r) sc[h][r] += __shfl_xor(sc[h][r], m, 64);
        }
        if (lrow < 4) {
            int r = lrow;
            sc_lds[wid][gq * 4 + r] = make_float4(sc[0][r], sc[1][r], sc[2][r], sc[3][r]);
        }
        __syncthreads();
        if (t < 16) {
            int row = r0 + t;
            if (row < n) {
                float4 s0 = sc_lds[0][t], s1 = sc_lds[1][t];
                float4 s2 = sc_lds[2][t], s3 = sc_lds[3][t];
                *(float4*)&snext[(size_t)row * 4] =
                    make_float4(s0.x + s1.x + s2.x + s3.x + cnext[0],
                                s0.y + s1.y + s2.y + s3.y + cnext[1],
                                s0.z + s1.z + s2.z + s3.z + cnext[2],
                                s0.w + s1.w + s2.w + s3.w + cnext[3]);
            }
        }
    }
}

// ---------------- launch ----------------

extern "C" void kernel_launch(void* const* d_in, const int* in_sizes, int n_in,
                              void* d_out, int out_size, void* d_ws, size_t ws_size,
                              hipStream_t stream) {
    const float* x    = (const float*)d_in[0];
    const int*   ei   = (const int*)d_in[1];
    const float* ew   = (const float*)d_in[2];
    const float* W1   = (const float*)d_in[3];
    const float* b1   = (const float*)d_in[4];
    const float* att1 = (const float*)d_in[5];
    const float* W2   = (const float*)d_in[6];
    const float* b2   = (const float*)d_in[7];
    const float* att2 = (const float*)d_in[8];
    const float* W3   = (const float*)d_in[9];
    const float* b3   = (const float*)d_in[10];
    const float* att3 = (const float*)d_in[11];

    const int N = in_sizes[0] / 128;
    const int E = in_sizes[2];
    const int* src = ei;
    const int* dst = ei + E;

    char* wp = (char*)d_ws;
    auto alloc = [&](size_t bytes) -> void* {
        void* p = (void*)wp;
        wp += (bytes + 511) & ~(size_t)511;
        return p;
    };
    int*   deg    = (int*)alloc((size_t)N * 4);
    int*   rowptr = (int*)alloc((size_t)(N + 1) * 4);
    int*   fill   = (int*)alloc((size_t)N * 4);
    int*   bsum   = (int*)alloc(256 * 4);
    int*   boff   = (int*)alloc(256 * 4);
    int*   srcs   = (int*)alloc((size_t)E * 4);
    float* wsrt   = (float*)alloc((size_t)E * 4);
    unsigned* xb  = (unsigned*)alloc((size_t)N * 64 * 4);
    float* s      = (float*)alloc((size_t)N * 4 * 4);
    float* s2     = (float*)alloc((size_t)N * 4 * 4);
    float* alpha  = (float*)alloc((size_t)E * 4 * 4);
    unsigned short* a1 = (unsigned short*)alloc((size_t)N * 64 * 2);
    unsigned short* a2 = (unsigned short*)alloc((size_t)N * 64 * 2);
    float* v1 = (float*)alloc(512 * 4);
    float* v2 = (float*)alloc(256 * 4);
    float* v3 = (float*)alloc(256 * 4);
    float* c1 = (float*)alloc(16);
    float* c2 = (float*)alloc(16);
    float* c3 = (float*)alloc(16);
    unsigned short* Ws1 = (unsigned short*)alloc(32768 * 2);
    unsigned short* Ws2 = (unsigned short*)alloc(16384 * 2);
    unsigned short* Ws3 = (unsigned short*)alloc(32768 * 2);

    // --- prep (independent of CSR) ---
    wpack3_k<<<320, 256, 0, stream>>>(W1, W2, W3, Ws1, Ws2, Ws3);
    prep_k<<<5, 256, 0, stream>>>(W1, att1, b1, W2, att2, b2, W3, att3, b3,
                                  v1, v2, v3, c1, c2, c3);
    int gx = (N * 64 + 255) / 256;
    xpack_score_k<<<gx, 256, 0, stream>>>(x, v1, c1, xb, s, N);

    // --- CSR build (shared by all 3 layers) ---
    hipMemsetAsync(deg, 0, (size_t)N * 4, stream);
    int ge = (E + 255) / 256;
    int nb = (N + 2047) / 2048;
    hist_k<<<ge, 256, 0, stream>>>(dst, deg, E);
    partial_k<<<nb, 256, 0, stream>>>(deg, bsum, N);
    bscan_k<<<1, 256, 0, stream>>>(bsum, boff, nb);
    rescan_k<<<nb, 256, 0, stream>>>(deg, boff, rowptr, fill, N, E);
    scatter_k<<<ge, 256, 0, stream>>>(src, dst, ew, fill, srcs, wsrt, E);

    int gf = (N + 15) / 16;

    // --- layer 1 ---
    alpha_k<<<ge, 256, 0, stream>>>(srcs, wsrt, s, alpha, E);
    fused_k<128, 64, false><<<gf, 256, 0, stream>>>(rowptr, srcs, alpha, xb, Ws1, b1,
                                                    v2, c2, a1, nullptr, s2, N);

    // --- layer 2 ---
    alpha_k<<<ge, 256, 0, stream>>>(srcs, wsrt, s2, alpha, E);
    fused_k<64, 64, false><<<gf, 256, 0, stream>>>(rowptr, srcs, alpha, (const unsigned*)a1,
                                                   Ws2, b2, v3, c3, a2, nullptr, s, N);

    // --- layer 3 ---
    alpha_k<<<ge, 256, 0, stream>>>(srcs, wsrt, s, alpha, E);
    fused_k<64, 128, true><<<gf, 256, 0, stream>>>(rowptr, srcs, alpha, (const unsigned*)a2,
                                                   Ws3, b3, nullptr, nullptr, nullptr,
                                                   (float*)d_out, nullptr, N);
}

// Round 14
// 241.697 us; speedup vs baseline: 1.2054x; 1.0857x over previous
//
#include <hip/hip_runtime.h>
#include <hip/hip_bf16.h>

#define NHEAD 4
#define NEG 0.2f

typedef __bf16 bf16x8 __attribute__((ext_vector_type(8)));
typedef __bf16 bf16x4 __attribute__((ext_vector_type(4)));
typedef float f32x4 __attribute__((ext_vector_type(4)));

__device__ __forceinline__ float blo(unsigned u) { return __uint_as_float(u << 16); }
__device__ __forceinline__ float bhi(unsigned u) { return __uint_as_float(u & 0xffff0000u); }
__device__ __forceinline__ unsigned short fbits(float f) {
    __bf16 h = (__bf16)f;
    return *(unsigned short*)&h;
}

// ---------------- CSR build ----------------

__global__ __launch_bounds__(256) void hist_k(const int* __restrict__ dst,
                                              int* __restrict__ deg, int E) {
    int e = blockIdx.x * 256 + threadIdx.x;
    if (e < E) atomicAdd(&deg[dst[e]], 1);
}

__global__ __launch_bounds__(256) void partial_k(const int* __restrict__ deg,
                                                 int* __restrict__ bsum, int n) {
    int t = threadIdx.x;
    int base = blockIdx.x * 2048 + t * 8;
    int s = 0;
#pragma unroll
    for (int i = 0; i < 8; ++i) {
        int idx = base + i;
        if (idx < n) s += deg[idx];
    }
#pragma unroll
    for (int off = 32; off; off >>= 1) s += __shfl_down(s, off, 64);
    __shared__ int ws[4];
    if ((t & 63) == 0) ws[t >> 6] = s;
    __syncthreads();
    if (t == 0) bsum[blockIdx.x] = ws[0] + ws[1] + ws[2] + ws[3];
}

__global__ __launch_bounds__(256) void bscan_k(const int* __restrict__ bsum,
                                               int* __restrict__ boff, int nb) {
    __shared__ int sh[256];
    int t = threadIdx.x;
    int v = (t < nb) ? bsum[t] : 0;
    sh[t] = v;
    __syncthreads();
    for (int off = 1; off < 256; off <<= 1) {
        int u = (t >= off) ? sh[t - off] : 0;
        __syncthreads();
        sh[t] += u;
        __syncthreads();
    }
    if (t < nb) boff[t] = sh[t] - v;  // exclusive
}

__global__ __launch_bounds__(256) void rescan_k(const int* __restrict__ deg,
                                                const int* __restrict__ boff,
                                                int* __restrict__ rowptr,
                                                int* __restrict__ fill,
                                                int n, int total) {
    __shared__ int ts[256];
    int t = threadIdx.x;
    int base = blockIdx.x * 2048 + t * 8;
    int v[8];
    int s = 0;
#pragma unroll
    for (int i = 0; i < 8; ++i) {
        int idx = base + i;
        v[i] = (idx < n) ? deg[idx] : 0;
        s += v[i];
    }
    ts[t] = s;
    __syncthreads();
    for (int off = 1; off < 256; off <<= 1) {
        int u = (t >= off) ? ts[t - off] : 0;
        __syncthreads();
        ts[t] += u;
        __syncthreads();
    }
    int run = boff[blockIdx.x] + ts[t] - s;
#pragma unroll
    for (int i = 0; i < 8; ++i) {
        int idx = base + i;
        if (idx < n) {
            rowptr[idx] = run;
            fill[idx] = run;
            run += v[i];
        }
    }
    if (blockIdx.x == 0 && t == 0) rowptr[n] = total;
}

__global__ __launch_bounds__(256) void scatter_k(const int* __restrict__ src,
                                                 const int* __restrict__ dst,
                                                 const float* __restrict__ ew,
                                                 int* __restrict__ fill,
                                                 int* __restrict__ srcs,
                                                 float* __restrict__ wsrt, int E) {
    int e = blockIdx.x * 256 + threadIdx.x;
    if (e < E) {
        int d = dst[e];
        int p = atomicAdd(&fill[d], 1);
        srcs[p] = src[e];
        wsrt[p] = ew[e];
    }
}

// ---------------- prep: v_h = W_h . att_h, c_h = b_h . att_h (all 3 layers) ----------------

__global__ __launch_bounds__(256) void prep_k(const float* __restrict__ W1, const float* __restrict__ att1, const float* __restrict__ b1,
                                              const float* __restrict__ W2, const float* __restrict__ att2, const float* __restrict__ b2,
                                              const float* __restrict__ W3, const float* __restrict__ att3, const float* __restrict__ b3,
                                              float* __restrict__ v1, float* __restrict__ v2, float* __restrict__ v3,
                                              float* __restrict__ c1, float* __restrict__ c2, float* __restrict__ c3) {
    int tid = blockIdx.x * 256 + threadIdx.x;
    if (tid < 512) {
        int h = tid >> 7, k = tid & 127;
        float p = 0.f;
        for (int d = 0; d < 64; ++d) p += W1[k * 256 + h * 64 + d] * att1[h * 64 + d];
        v1[h * 128 + k] = p;
    } else if (tid < 768) {
        int t = tid - 512, h = t >> 6, k = t & 63;
        float p = 0.f;
        for (int d = 0; d < 64; ++d) p += W2[k * 256 + h * 64 + d] * att2[h * 64 + d];
        v2[h * 64 + k] = p;
    } else if (tid < 1024) {
        int t = tid - 768, h = t >> 6, k = t & 63;
        float p = 0.f;
        for (int d = 0; d < 128; ++d) p += W3[k * 512 + h * 128 + d] * att3[h * 128 + d];
        v3[h * 64 + k] = p;
    } else if (tid < 1028) {
        int h = tid - 1024;
        float p = 0.f;
        for (int d = 0; d < 64; ++d) p += b1[h * 64 + d] * att1[h * 64 + d];
        c1[h] = p;
    } else if (tid < 1032) {
        int h = tid - 1028;
        float p = 0.f;
        for (int d = 0; d < 64; ++d) p += b2[h * 64 + d] * att2[h * 64 + d];
        c2[h] = p;
    } else if (tid < 1036) {
        int h = tid - 1032;
        float p = 0.f;
        for (int d = 0; d < 128; ++d) p += b3[h * 128 + d] * att3[h * 128 + d];
        c3[h] = p;
    }
}

// ---------------- stacked W packs: Ws[d][h*K+k] = W[k][h*D+d], bf16 ----------------

__global__ __launch_bounds__(256) void wpack3_k(const float* __restrict__ W1,
                                                const float* __restrict__ W2,
                                                const float* __restrict__ W3,
                                                unsigned short* __restrict__ Ws1,
                                                unsigned short* __restrict__ Ws2,
                                                unsigned short* __restrict__ Ws3) {
    int tid = blockIdx.x * 256 + threadIdx.x;
    if (tid < 32768) {
        int d = tid >> 9, r = tid & 511, h = r >> 7, k = r & 127;
        Ws1[tid] = fbits(W1[k * 256 + h * 64 + d]);
    } else if (tid < 49152) {
        int t = tid - 32768;
        int d = t >> 8, r = t & 255, h = r >> 6, k = r & 63;
        Ws2[t] = fbits(W2[k * 256 + h * 64 + d]);
    } else if (tid < 81920) {
        int t = tid - 49152;
        int d = t >> 8, r = t & 255, h = r >> 6, k = r & 63;
        Ws3[t] = fbits(W3[k * 512 + h * 128 + d]);
    }
}

// ---------------- x pack to bf16 + layer-1 scores ----------------

__global__ __launch_bounds__(256) void xpack_score_k(const float* __restrict__ x,
                                                     const float* __restrict__ v1,
                                                     const float* __restrict__ c1,
                                                     unsigned* __restrict__ xb,
                                                     float* __restrict__ s, int n) {
    int gt = blockIdx.x * 256 + threadIdx.x;
    int node = gt >> 6, lane = gt & 63;
    if (node >= n) return;
    float2 xv = ((const float2*)(x + (size_t)node * 128))[lane];
    xb[(size_t)node * 64 + lane] = (unsigned)fbits(xv.x) | ((unsigned)fbits(xv.y) << 16);
    int d0 = 2 * lane;
    float p0 = xv.x * v1[0 * 128 + d0] + xv.y * v1[0 * 128 + d0 + 1];
    float p1 = xv.x * v1[1 * 128 + d0] + xv.y * v1[1 * 128 + d0 + 1];
    float p2 = xv.x * v1[2 * 128 + d0] + xv.y * v1[2 * 128 + d0 + 1];
    float p3 = xv.x * v1[3 * 128 + d0] + xv.y * v1[3 * 128 + d0 + 1];
#pragma unroll
    for (int off = 32; off; off >>= 1) {
        p0 += __shfl_xor(p0, off, 64);
        p1 += __shfl_xor(p1, off, 64);
        p2 += __shfl_xor(p2, off, 64);
        p3 += __shfl_xor(p3, off, 64);
    }
    if (lane == 0)
        *(float4*)&s[(size_t)node * 4] = make_float4(p0 + c1[0], p1 + c1[1], p2 + c1[2], p3 + c1[3]);
}

// ---------------- fused layer: per-chunk {edge-parallel alpha -> LDS; gather} ->
//                  LDS stage (split bf16, XOR-swizzled) -> MFMA -> epilogue ----------------
// Block = 16 nodes; their edges are contiguous [rowptr[r0], rowptr[r0+16]).
// Alpha computed once per edge (256 threads edge-parallel), consumed from LDS.

template <int K, int D, bool LAST>
__global__ __launch_bounds__(256, 4) void fused_k(const int* __restrict__ rowptr,
                                                  const int* __restrict__ srcs,
                                                  const float* __restrict__ wsrt,
                                                  const float* __restrict__ sprev,
                                                  const unsigned* __restrict__ xb,
                                                  const unsigned short* __restrict__ Ws,
                                                  const float* __restrict__ bias,
                                                  const float* __restrict__ vnext,
                                                  const float* __restrict__ cnext,
                                                  unsigned short* __restrict__ aout,
                                                  float* __restrict__ fout,
                                                  float* __restrict__ snext,
                                                  int n) {
    constexpr int HK = 4 * K;
    constexpr int KS = HK / 32;
    constexpr int NC = D / 16;
    constexpr int CW = NC / 4;
    constexpr int DW = K / 32;
    constexpr int CHUNK = 256;

    __shared__ __bf16 gh[16 * HK];
    __shared__ __bf16 gl[16 * HK];
    __shared__ float4 al_lds[CHUNK];
    __shared__ float4 A_lds[16];
    __shared__ float4 sc_lds[4][16];

    int t = threadIdx.x;
    int r0 = blockIdx.x * 16;
    int n4 = t >> 4, sl = t & 15;
    int node = r0 + n4;

    // block edge range (contiguous across the 16 nodes)
    int hi = min(r0 + 16, n);
    int eb = rowptr[r0];
    int ee = rowptr[hi];

    int beg = 0, end = 0;
    if (node < n) { beg = rowptr[node]; end = rowptr[node + 1]; }

    // ---- gather accumulators ----
    float acc[4][2 * DW];
#pragma unroll
    for (int h = 0; h < 4; ++h)
#pragma unroll
        for (int j = 0; j < 2 * DW; ++j) acc[h][j] = 0.f;
    float4 aA = make_float4(0.f, 0.f, 0.f, 0.f);

    auto load_u = [&](int sn, unsigned* u) {
        if constexpr (DW == 4) {
            uint4 ta = ((const uint4*)xb)[(size_t)sn * 16 + sl];
            u[0] = ta.x; u[1] = ta.y; u[2] = ta.z; u[3] = ta.w;
        } else {
            uint2 ta = ((const uint2*)xb)[(size_t)sn * 16 + sl];
            u[0] = ta.x; u[1] = ta.y;
        }
    };
    auto accum = [&](float4 al, const unsigned* u) {
#pragma unroll
        for (int j = 0; j < DW; ++j) {
            float x0 = blo(u[j]), x1 = bhi(u[j]);
            acc[0][2 * j] += al.x * x0; acc[0][2 * j + 1] += al.x * x1;
            acc[1][2 * j] += al.y * x0; acc[1][2 * j + 1] += al.y * x1;
            acc[2][2 * j] += al.z * x0; acc[2][2 * j + 1] += al.z * x1;
            acc[3][2 * j] += al.w * x0; acc[3][2 * j + 1] += al.w * x1;
        }
        aA.x += al.x; aA.y += al.y; aA.z += al.z; aA.w += al.w;
    };

    // ---- chunked: edge-parallel alpha into LDS, then per-node gather ----
    for (int cs = eb; cs < ee; cs += CHUNK) {
        int ce = min(cs + CHUNK, ee);
        {
            int i = cs + t;
            if (i < ce) {
                int sn = srcs[i];
                float w = wsrt[i];
                float4 sv = *(const float4*)&sprev[(size_t)sn * 4];
                float a0 = (sv.x > 0.f ? sv.x : NEG * sv.x) * w;
                float a1 = (sv.y > 0.f ? sv.y : NEG * sv.y) * w;
                float a2 = (sv.z > 0.f ? sv.z : NEG * sv.z) * w;
                float a3 = (sv.w > 0.f ? sv.w : NEG * sv.w) * w;
                float m = fmaxf(fmaxf(a0, a1), fmaxf(a2, a3));
                float e0 = __expf(a0 - m), e1 = __expf(a1 - m);
                float e2 = __expf(a2 - m), e3 = __expf(a3 - m);
                float inv = 0.25f / (e0 + e1 + e2 + e3);
                al_lds[i - cs] = make_float4(e0 * inv, e1 * inv, e2 * inv, e3 * inv);
            }
        }
        __syncthreads();

        int gb = max(beg, cs), ge = min(end, ce);
        int e = gb;
        for (; e + 3 < ge; e += 4) {
            int sn0 = srcs[e], sn1 = srcs[e + 1], sn2 = srcs[e + 2], sn3 = srcs[e + 3];
            unsigned u0[DW], u1[DW], u2[DW], u3[DW];
            load_u(sn0, u0); load_u(sn1, u1); load_u(sn2, u2); load_u(sn3, u3);
            float4 al0 = al_lds[e - cs];
            float4 al1 = al_lds[e + 1 - cs];
            float4 al2 = al_lds[e + 2 - cs];
            float4 al3 = al_lds[e + 3 - cs];
            accum(al0, u0); accum(al1, u1); accum(al2, u2); accum(al3, u3);
        }
        for (; e < ge; ++e) {
            int sn = srcs[e];
            unsigned u[DW];
            load_u(sn, u);
            float4 al = al_lds[e - cs];
            accum(al, u);
        }
        __syncthreads();
    }

    // ---- split hi/lo into LDS (XOR-swizzled: byte ^= (row&7)<<4) ----
    {
        char* ghb = (char*)gh + (size_t)n4 * (HK * 2);
        char* glb = (char*)gl + (size_t)n4 * (HK * 2);
        int sw = (n4 & 7) << 4;
#pragma unroll
        for (int h = 0; h < 4; ++h) {
            if constexpr (DW == 4) {
                bf16x8 vh, vl;
#pragma unroll
                for (int j = 0; j < 8; ++j) {
                    __bf16 hiw = (__bf16)acc[h][j];
                    vh[j] = hiw;
                    vl[j] = (__bf16)(acc[h][j] - (float)hiw);
                }
                int bo = (h * K + sl * 8) * 2;
                *(bf16x8*)(ghb + (bo ^ sw)) = vh;
                *(bf16x8*)(glb + (bo ^ sw)) = vl;
            } else {
                bf16x4 vh, vl;
#pragma unroll
                for (int j = 0; j < 4; ++j) {
                    __bf16 hiw = (__bf16)acc[h][j];
                    vh[j] = hiw;
                    vl[j] = (__bf16)(acc[h][j] - (float)hiw);
                }
                int bo = (h * K + sl * 4) * 2;
                *(bf16x4*)(ghb + (bo ^ sw)) = vh;
                *(bf16x4*)(glb + (bo ^ sw)) = vl;
            }
        }
        if (sl == 0) A_lds[n4] = aA;
    }
    __syncthreads();

    // ---- MFMA phase: D-split across waves ----
    int wid = t >> 6, lane = t & 63;
    int lrow = lane & 15, gq = lane >> 4;

    f32x4 acc2[CW];
#pragma unroll
    for (int cw = 0; cw < CW; ++cw)
#pragma unroll
        for (int r = 0; r < 4; ++r) acc2[cw][r] = 0.f;

    const __bf16* wsp = (const __bf16*)Ws;
    const char* ghr = (const char*)gh + (size_t)lrow * (HK * 2);
    const char* glr = (const char*)gl + (size_t)lrow * (HK * 2);
    int swr = (lrow & 7) << 4;
#pragma unroll
    for (int ks = 0; ks < KS; ++ks) {
        int bo = ks * 64 + gq * 16;
        bf16x8 fh = *(const bf16x8*)(ghr + (bo ^ swr));
        bf16x8 fl = *(const bf16x8*)(glr + (bo ^ swr));
#pragma unroll
        for (int cw = 0; cw < CW; ++cw) {
            int c = wid * CW + cw;
            bf16x8 bfr = *(const bf16x8*)(wsp + (size_t)(c * 16 + lrow) * HK + ks * 32 + gq * 8);
            acc2[cw] = __builtin_amdgcn_mfma_f32_16x16x32_bf16(fh, bfr, acc2[cw], 0, 0, 0);
            acc2[cw] = __builtin_amdgcn_mfma_f32_16x16x32_bf16(fl, bfr, acc2[cw], 0, 0, 0);
        }
    }

    // ---- epilogue ----
    float4 Ar[4];
#pragma unroll
    for (int r = 0; r < 4; ++r) Ar[r] = A_lds[gq * 4 + r];

    float sc[4][4];
#pragma unroll
    for (int h = 0; h < 4; ++h)
#pragma unroll
        for (int r = 0; r < 4; ++r) sc[h][r] = 0.f;

#pragma unroll
    for (int cw = 0; cw < CW; ++cw) {
        int col = (wid * CW + cw) * 16 + lrow;
        float bb0 = bias[0 * D + col], bb1 = bias[1 * D + col];
        float bb2 = bias[2 * D + col], bb3 = bias[3 * D + col];
        float vv0 = 0.f, vv1 = 0.f, vv2 = 0.f, vv3 = 0.f;
        if constexpr (!LAST) {
            vv0 = vnext[0 * D + col]; vv1 = vnext[1 * D + col];
            vv2 = vnext[2 * D + col]; vv3 = vnext[3 * D + col];
        }
#pragma unroll
        for (int r = 0; r < 4; ++r) {
            float val = acc2[cw][r] + Ar[r].x * bb0 + Ar[r].y * bb1 + Ar[r].z * bb2 + Ar[r].w * bb3;
            int row = r0 + gq * 4 + r;
            if constexpr (LAST) {
                if (row < n) fout[(size_t)row * D + col] = val;
            } else {
                val = fmaxf(val, 0.f);
                if (row < n) aout[(size_t)row * D + col] = fbits(val);
                sc[0][r] += val * vv0;
                sc[1][r] += val * vv1;
                sc[2][r] += val * vv2;
                sc[3][r] += val * vv3;
            }
        }
    }

    if constexpr (!LAST) {
#pragma unroll
        for (int m = 1; m < 16; m <<= 1) {
#pragma unroll
            for (int h = 0; h < 4; ++h)
#pragma unroll
                for (int r = 0; r < 4; ++r) sc[h][r] += __shfl_xor(sc[h][r], m, 64);
        }
        if (lrow < 4) {
            int r = lrow;
            sc_lds[wid][gq * 4 + r] = make_float4(sc[0][r], sc[1][r], sc[2][r], sc[3][r]);
        }
        __syncthreads();
        if (t < 16) {
            int row = r0 + t;
            if (row < n) {
                float4 s0 = sc_lds[0][t], s1 = sc_lds[1][t];
                float4 s2 = sc_lds[2][t], s3 = sc_lds[3][t];
                *(float4*)&snext[(size_t)row * 4] =
                    make_float4(s0.x + s1.x + s2.x + s3.x + cnext[0],
                                s0.y + s1.y + s2.y + s3.y + cnext[1],
                                s0.z + s1.z + s2.z + s3.z + cnext[2],
                                s0.w + s1.w + s2.w + s3.w + cnext[3]);
            }
        }
    }
}

// ---------------- launch ----------------

extern "C" void kernel_launch(void* const* d_in, const int* in_sizes, int n_in,
                              void* d_out, int out_size, void* d_ws, size_t ws_size,
                              hipStream_t stream) {
    const float* x    = (const float*)d_in[0];
    const int*   ei   = (const int*)d_in[1];
    const float* ew   = (const float*)d_in[2];
    const float* W1   = (const float*)d_in[3];
    const float* b1   = (const float*)d_in[4];
    const float* att1 = (const float*)d_in[5];
    const float* W2   = (const float*)d_in[6];
    const float* b2   = (const float*)d_in[7];
    const float* att2 = (const float*)d_in[8];
    const float* W3   = (const float*)d_in[9];
    const float* b3   = (const float*)d_in[10];
    const float* att3 = (const float*)d_in[11];

    const int N = in_sizes[0] / 128;
    const int E = in_sizes[2];
    const int* src = ei;
    const int* dst = ei + E;

    char* wp = (char*)d_ws;
    auto alloc = [&](size_t bytes) -> void* {
        void* p = (void*)wp;
        wp += (bytes + 511) & ~(size_t)511;
        return p;
    };
    int*   deg    = (int*)alloc((size_t)N * 4);
    int*   rowptr = (int*)alloc((size_t)(N + 1) * 4);
    int*   fill   = (int*)alloc((size_t)N * 4);
    int*   bsum   = (int*)alloc(256 * 4);
    int*   boff   = (int*)alloc(256 * 4);
    int*   srcs   = (int*)alloc((size_t)E * 4);
    float* wsrt   = (float*)alloc((size_t)E * 4);
    unsigned* xb  = (unsigned*)alloc((size_t)N * 64 * 4);
    float* s      = (float*)alloc((size_t)N * 4 * 4);
    float* s2     = (float*)alloc((size_t)N * 4 * 4);
    unsigned short* a1 = (unsigned short*)alloc((size_t)N * 64 * 2);
    unsigned short* a2 = (unsigned short*)alloc((size_t)N * 64 * 2);
    float* v1 = (float*)alloc(512 * 4);
    float* v2 = (float*)alloc(256 * 4);
    float* v3 = (float*)alloc(256 * 4);
    float* c1 = (float*)alloc(16);
    float* c2 = (float*)alloc(16);
    float* c3 = (float*)alloc(16);
    unsigned short* Ws1 = (unsigned short*)alloc(32768 * 2);
    unsigned short* Ws2 = (unsigned short*)alloc(16384 * 2);
    unsigned short* Ws3 = (unsigned short*)alloc(32768 * 2);

    // --- prep (independent of CSR) ---
    wpack3_k<<<320, 256, 0, stream>>>(W1, W2, W3, Ws1, Ws2, Ws3);
    prep_k<<<5, 256, 0, stream>>>(W1, att1, b1, W2, att2, b2, W3, att3, b3,
                                  v1, v2, v3, c1, c2, c3);
    int gx = (N * 64 + 255) / 256;
    xpack_score_k<<<gx, 256, 0, stream>>>(x, v1, c1, xb, s, N);

    // --- CSR build (shared by all 3 layers) ---
    hipMemsetAsync(deg, 0, (size_t)N * 4, stream);
    int ge = (E + 255) / 256;
    int nb = (N + 2047) / 2048;
    hist_k<<<ge, 256, 0, stream>>>(dst, deg, E);
    partial_k<<<nb, 256, 0, stream>>>(deg, bsum, N);
    bscan_k<<<1, 256, 0, stream>>>(bsum, boff, nb);
    rescan_k<<<nb, 256, 0, stream>>>(deg, boff, rowptr, fill, N, E);
    scatter_k<<<ge, 256, 0, stream>>>(src, dst, ew, fill, srcs, wsrt, E);

    int gf = (N + 15) / 16;

    // --- layer 1: gather x (K=128), scores from s -> write a1 + s2 ---
    fused_k<128, 64, false><<<gf, 256, 0, stream>>>(rowptr, srcs, wsrt, s, xb, Ws1, b1,
                                                    v2, c2, a1, nullptr, s2, N);

    // --- layer 2: gather a1 (K=64), scores from s2 -> write a2 + s ---
    fused_k<64, 64, false><<<gf, 256, 0, stream>>>(rowptr, srcs, wsrt, s2, (const unsigned*)a1,
                                                   Ws2, b2, v3, c3, a2, nullptr, s, N);

    // --- layer 3: gather a2 (K=64), scores from s -> write d_out ---
    fused_k<64, 128, true><<<gf, 256, 0, stream>>>(rowptr, srcs, wsrt, s, (const unsigned*)a2,
                                                   Ws3, b3, nullptr, nullptr, nullptr,
                                                   (float*)d_out, nullptr, N);
}